// Round 10
// baseline (214.018 us; speedup 1.0000x reference)
//
#include <hip/hip_runtime.h>
#include <hip/hip_bf16.h>
#include <math.h>

typedef __bf16 bf16_t;
typedef __bf16 bf16x8 __attribute__((ext_vector_type(8)));
typedef float f32x4 __attribute__((ext_vector_type(4)));

__device__ __forceinline__ void gload_lds16(const void* g, void* l) {
  __builtin_amdgcn_global_load_lds((const __attribute__((address_space(1))) void*)g,
                                   (__attribute__((address_space(3))) void*)l, 16, 0, 0);
}

// ---------------- cast fp32 -> bf16 (vectorized x8) ----------------
__global__ void castk(const float* __restrict__ in, bf16_t* __restrict__ out, int n) {
  int i = (blockIdx.x * blockDim.x + threadIdx.x) * 8;
  if (i >= n) return;
  float4 a = *(const float4*)(in + i);
  float4 b = *(const float4*)(in + i + 4);
  bf16x8 o;
  o[0] = (bf16_t)a.x; o[1] = (bf16_t)a.y; o[2] = (bf16_t)a.z; o[3] = (bf16_t)a.w;
  o[4] = (bf16_t)b.x; o[5] = (bf16_t)b.y; o[6] = (bf16_t)b.z; o[7] = (bf16_t)b.w;
  *(bf16x8*)(out + i) = o;
}

// ------------- transpose + cast: in fp32 [K][N] -> out bf16 [N][K] -------------
__global__ void transk(const float* __restrict__ in, bf16_t* __restrict__ out,
                       int K, int N) {
  __shared__ float t[32][33];
  int n0 = blockIdx.x * 32, k0 = blockIdx.y * 32;
  int tx = threadIdx.x & 31, ty = threadIdx.x >> 5;  // ty 0..7
#pragma unroll
  for (int r = ty; r < 32; r += 8) t[r][tx] = in[(size_t)(k0 + r) * N + n0 + tx];
  __syncthreads();
#pragma unroll
  for (int r = ty; r < 32; r += 8)
    out[(size_t)(n0 + r) * K + k0 + tx] = (bf16_t)t[tx][r];
}

// ------------- row offsets: ro[n] = lower_bound(dst, n) (dst sorted) -------------
__global__ void rowoffk(const int* __restrict__ dst, int* __restrict__ ro, int N, int E) {
  int n = blockIdx.x * blockDim.x + threadIdx.x;
  if (n > N) return;
  if (n == N) { ro[N] = E; return; }
  int lo = 0, hi = E;
  while (lo < hi) { int mid = (lo + hi) >> 1; if (dst[mid] < n) lo = mid + 1; else hi = mid; }
  ro[n] = lo;
}

// ------------- el/er: per node, per head dot(h, al), dot(h, ar) -------------
__global__ void elerk(const bf16_t* __restrict__ Hb, const float* __restrict__ al,
                      const float* __restrict__ ar, float* __restrict__ el,
                      float* __restrict__ er, int N) {
  int node = blockIdx.x * 4 + (threadIdx.x >> 6);
  int lane = threadIdx.x & 63;
  if (node >= N) return;
  bf16x8 v = *(const bf16x8*)(Hb + (size_t)node * 512 + lane * 8);
  int head = lane >> 4;
  int dbase = (lane & 15) * 8;
  float sl = 0.f, sr = 0.f;
#pragma unroll
  for (int t = 0; t < 8; t++) {
    float f = (float)v[t];
    sl += f * al[head * 128 + dbase + t];
    sr += f * ar[head * 128 + dbase + t];
  }
#pragma unroll
  for (int off = 1; off < 16; off <<= 1) {
    sl += __shfl_xor(sl, off);
    sr += __shfl_xor(sr, off);
  }
  if ((lane & 15) == 0) {
    el[node * 4 + head] = sl;
    er[node * 4 + head] = sr;
  }
}

// ------------- edge weights (edge-parallel, streaming), per-head PLANES -------
// pw[h*E + e] = exp(leaky_relu(el[src[e]][h] + er[dst[e]][h]))
// Max-subtraction dropped (shift-invariant; scores are O(few sigma), fp32-safe).
__global__ void edgek(const float* __restrict__ el, const float* __restrict__ er,
                      const int* __restrict__ src, const int* __restrict__ dst,
                      float* __restrict__ pw, int E) {
  int e = blockIdx.x * blockDim.x + threadIdx.x;
  if (e >= E) return;
  int s = src[e], d = dst[e];
  float4 ev = *(const float4*)(el + (size_t)s * 4);
  float4 rv = *(const float4*)(er + (size_t)d * 4);
  float c;
  c = ev.x + rv.x; c = c >= 0.f ? c : 0.2f * c; pw[e] = __expf(c);
  c = ev.y + rv.y; c = c >= 0.f ? c : 0.2f * c; pw[(size_t)E + e] = __expf(c);
  c = ev.z + rv.z; c = c >= 0.f ? c : 0.2f * c; pw[(size_t)2 * E + e] = __expf(c);
  c = ev.w + rv.w; c = c >= 0.f ? c : 0.2f * c; pw[(size_t)3 * E + e] = __expf(c);
}

// ------------- gather-aggregate, DIM-SLICE x XCD partitioned, batch-8 ----------
// slice = blockIdx.x & 7 -> round-robin XCD mapping pins each 64-dim slice of
// Hb (2.56 MB) into one XCD's 4 MB L2 (verified: FETCH 140->24 MB in r6).
// lane = g*8 + oct; batch-8 contiguous src/ph loads resolve 8 gather addresses
// at once (verified: gatherk left top-5 in r8, ~20 us each).
#define GK_NPB 32  // nodes per block (4 waves x 8 groups); 20000 = 625*32
__global__ __launch_bounds__(256) void gatherk(
    const bf16_t* __restrict__ Hb, const float* __restrict__ pw,
    const int* __restrict__ src, const int* __restrict__ ro,
    const float* __restrict__ bias, bf16_t* __restrict__ out, int N, int E) {
  const int slice = blockIdx.x & 7;
  const int group = blockIdx.x >> 3;
  const int w = threadIdx.x >> 6, lane = threadIdx.x & 63;
  const int g = lane >> 3;               // node sub-index within wave
  const int oct = lane & 7;              // dim octet within slice
  const int head = slice >> 1;
  const float* __restrict__ ph = pw + (size_t)head * E;
  const int dimbase = slice * 64 + oct * 8;

  const int n = group * GK_NPB + w * 8 + g;
  const int e0 = ro[n], e1 = ro[n + 1];

  float acc[8] = {0.f, 0.f, 0.f, 0.f, 0.f, 0.f, 0.f, 0.f};
  float psum = 0.f;

  for (int eb = e0 & ~7; eb < e1; eb += 8) {
    const int4 sv0 = *(const int4*)(src + eb);
    const int4 sv1 = *(const int4*)(src + eb + 4);
    const float4 pv0 = *(const float4*)(ph + eb);
    const float4 pv1 = *(const float4*)(ph + eb + 4);
    int ss[8]; float pp[8];
    ss[0] = sv0.x; ss[1] = sv0.y; ss[2] = sv0.z; ss[3] = sv0.w;
    ss[4] = sv1.x; ss[5] = sv1.y; ss[6] = sv1.z; ss[7] = sv1.w;
    pp[0] = pv0.x; pp[1] = pv0.y; pp[2] = pv0.z; pp[3] = pv0.w;
    pp[4] = pv1.x; pp[5] = pv1.y; pp[6] = pv1.z; pp[7] = pv1.w;
#pragma unroll
    for (int j = 0; j < 8; j++) {
      const int e = eb + j;
      if (e < e0 || e >= e1) pp[j] = 0.f;
    }
    bf16x8 v[8];
#pragma unroll
    for (int j = 0; j < 8; j++)
      v[j] = *(const bf16x8*)(Hb + (size_t)ss[j] * 512 + dimbase);
#pragma unroll
    for (int j = 0; j < 8; j++) {
      psum += pp[j];
#pragma unroll
      for (int t = 0; t < 8; t++) acc[t] += pp[j] * (float)v[j][t];
    }
  }

  const float ih = psum > 0.f ? 1.0f / psum : 0.f;
  const float4 b0 = *(const float4*)(bias + dimbase);
  const float4 b1 = *(const float4*)(bias + dimbase + 4);
  bf16x8 o; float vv;
  vv = acc[0] * ih + b0.x; o[0] = (bf16_t)(vv > 0.f ? vv : expm1f(vv));
  vv = acc[1] * ih + b0.y; o[1] = (bf16_t)(vv > 0.f ? vv : expm1f(vv));
  vv = acc[2] * ih + b0.z; o[2] = (bf16_t)(vv > 0.f ? vv : expm1f(vv));
  vv = acc[3] * ih + b0.w; o[3] = (bf16_t)(vv > 0.f ? vv : expm1f(vv));
  vv = acc[4] * ih + b1.x; o[4] = (bf16_t)(vv > 0.f ? vv : expm1f(vv));
  vv = acc[5] * ih + b1.y; o[5] = (bf16_t)(vv > 0.f ? vv : expm1f(vv));
  vv = acc[6] * ih + b1.z; o[6] = (bf16_t)(vv > 0.f ? vv : expm1f(vv));
  vv = acc[7] * ih + b1.w; o[7] = (bf16_t)(vv > 0.f ? vv : expm1f(vv));
  *(bf16x8*)(out + (size_t)n * 512 + dimbase) = o;
}

// ------------- bf16 MFMA GEMM: C[M][N] = A[M][K] @ Bt[N][K]^T -------------
// Grid-starvation fix (r9): templated BM/BN, small tiles -> 1256 blocks
// (4.9/CU) for the 512-wide GEMMs, 313 for the FC. XCD-chunked bijective
// swizzle, col-fastest in chunk -> A-panel stays in XCD L2 across the 8
// col-blocks. EPI=0: bf16 C. EPI=1: fp32 elu(C+bias) (final FC).
template <int BM, int BN, int WM, int WN, int EPI>
__global__ __launch_bounds__(256) void gemm_bt(
    const bf16_t* __restrict__ A, const bf16_t* __restrict__ Bt,
    void* __restrict__ C, const float* __restrict__ bias,
    int M, int N, int K) {
  constexpr int BK = 32;
  constexpr int WTM = BM / WM, WTN = BN / WN;
  constexpr int MF = WTM / 16, NF = WTN / 16;

  __shared__ bf16_t sA[BM][BK];
  __shared__ bf16_t sB[BN][BK];

  const int tid = threadIdx.x;
  const int wid = tid >> 6, lane = tid & 63;
  const int wr = wid / WN, wc = wid % WN;

  // XCD-chunked bijective swizzle (m204)
  const int nby = N / BN;
  const int nwg = gridDim.x;
  const int q = nwg >> 3, r = nwg & 7;
  const int xcd = blockIdx.x & 7, pos = blockIdx.x >> 3;
  const int wg = (xcd < r ? xcd * (q + 1) : r * (q + 1) + (xcd - r) * q) + pos;
  const int row0 = (wg / nby) * BM;
  const int col0 = (wg % nby) * BN;

  f32x4 acc[MF][NF];
#pragma unroll
  for (int i = 0; i < MF; i++)
#pragma unroll
    for (int j = 0; j < NF; j++) acc[i][j] = (f32x4){0.f, 0.f, 0.f, 0.f};

  const int lr = lane >> 2;          // row within 16-row staging group
  const int lkb = (lane & 3) * 8;    // k element offset for staging

  for (int k0 = 0; k0 < K; k0 += BK) {
#pragma unroll
    for (int i = 0; i < BM / 16; i += 4) {
      int r2 = (i + wid) * 16 + lr;
      int grow = row0 + r2; if (grow > M - 1) grow = M - 1;
      gload_lds16(A + (size_t)grow * K + k0 + lkb, &sA[(i + wid) * 16][0]);
    }
#pragma unroll
    for (int i = 0; i < BN / 16; i += 4) {
      int r2 = (i + wid) * 16 + lr;
      gload_lds16(Bt + (size_t)(col0 + r2) * K + k0 + lkb, &sB[(i + wid) * 16][0]);
    }
    __syncthreads();
    bf16x8 af[MF], bfr[NF];
#pragma unroll
    for (int i = 0; i < MF; i++)
      af[i] = *(const bf16x8*)&sA[wr * WTM + i * 16 + (lane & 15)][(lane >> 4) * 8];
#pragma unroll
    for (int j = 0; j < NF; j++)
      bfr[j] = *(const bf16x8*)&sB[wc * WTN + j * 16 + (lane & 15)][(lane >> 4) * 8];
#pragma unroll
    for (int i = 0; i < MF; i++)
#pragma unroll
      for (int j = 0; j < NF; j++)
        acc[i][j] = __builtin_amdgcn_mfma_f32_16x16x32_bf16(af[i], bfr[j], acc[i][j], 0, 0, 0);
    __syncthreads();
  }

#pragma unroll
  for (int i = 0; i < MF; i++) {
#pragma unroll
    for (int j = 0; j < NF; j++) {
#pragma unroll
      for (int rr = 0; rr < 4; rr++) {
        int row = row0 + wr * WTM + i * 16 + (lane >> 4) * 4 + rr;
        int col = col0 + wc * WTN + j * 16 + (lane & 15);
        if (row < M) {
          float v = acc[i][j][rr];
          if constexpr (EPI == 0) {
            ((bf16_t*)C)[(size_t)row * N + col] = (bf16_t)v;
          } else {
            v += bias[col];
            v = v > 0.f ? v : expm1f(v);
            ((float*)C)[(size_t)row * N + col] = v;
          }
        }
      }
    }
  }
}

extern "C" void kernel_launch(void* const* d_in, const int* in_sizes, int n_in,
                              void* d_out, int out_size, void* d_ws, size_t ws_size,
                              hipStream_t stream) {
  const float* feature = (const float*)d_in[0];
  const int* src = (const int*)d_in[1];
  const int* dst = (const int*)d_in[2];
  const float* W1 = (const float*)d_in[3];
  const float* al1 = (const float*)d_in[4];
  const float* ar1 = (const float*)d_in[5];
  const float* b1 = (const float*)d_in[6];
  const float* W2 = (const float*)d_in[7];
  const float* al2 = (const float*)d_in[8];
  const float* ar2 = (const float*)d_in[9];
  const float* b2 = (const float*)d_in[10];
  const float* Wfc = (const float*)d_in[11];
  const float* bfc = (const float*)d_in[12];

  const int N = 20000, E = 320000, INF = 1280, HD = 512;

  char* ws = (char*)d_ws;
  size_t off = 0;
  auto alloc = [&](size_t bytes) {
    void* p = ws + off;
    off += (bytes + 255) & ~(size_t)255;
    return p;
  };
  bf16_t* Xb  = (bf16_t*)alloc((size_t)N * INF * 2);   // 51.2 MB
  bf16_t* W1t = (bf16_t*)alloc((size_t)HD * INF * 2);
  bf16_t* W2t = (bf16_t*)alloc((size_t)HD * HD * 2);
  bf16_t* Wft = (bf16_t*)alloc((size_t)64 * HD * 2);
  bf16_t* Hb  = (bf16_t*)alloc((size_t)N * HD * 2);    // 20.5 MB
  bf16_t* Xn  = (bf16_t*)alloc((size_t)N * HD * 2);    // 20.5 MB
  float* el = (float*)alloc((size_t)N * 4 * 4);
  float* er = (float*)alloc((size_t)N * 4 * 4);
  float* pw = (float*)alloc((size_t)E * 4 * 4);        // 5.1 MB, planes [4][E]
  int* ro = (int*)alloc((size_t)(N + 1) * 4);

  // preprocessing
  castk<<<(N * INF) / (256 * 8), 256, 0, stream>>>(feature, Xb, N * INF);
  {
    dim3 g(HD / 32, INF / 32);
    transk<<<g, 256, 0, stream>>>(W1, W1t, INF, HD);
  }
  {
    dim3 g(HD / 32, HD / 32);
    transk<<<g, 256, 0, stream>>>(W2, W2t, HD, HD);
  }
  {
    dim3 g(64 / 32, HD / 32);
    transk<<<g, 256, 0, stream>>>(Wfc, Wft, HD, 64);
  }
  rowoffk<<<(N + 1 + 255) / 256, 256, 0, stream>>>(dst, ro, N, E);

  const int nbx = (N + 127) / 128;        // 157
  const int nbxf = (N + 63) / 64;         // 313
  const int gatherBlocks = (N / GK_NPB) * 8;   // 625 groups x 8 slices
  const int edgeBlocks = (E + 255) / 256;

  // layer 1: BN=64 -> 1256 blocks (4.9/CU)
  gemm_bt<128, 64, 2, 2, 0><<<nbx * (HD / 64), 256, 0, stream>>>(Xb, W1t, Hb, nullptr, N, HD, INF);
  elerk<<<N / 4, 256, 0, stream>>>(Hb, al1, ar1, el, er, N);
  edgek<<<edgeBlocks, 256, 0, stream>>>(el, er, src, dst, pw, E);
  gatherk<<<gatherBlocks, 256, 0, stream>>>(Hb, pw, src, ro, b1, Xn, N, E);

  // layer 2: BN=64 -> 1256 blocks
  gemm_bt<128, 64, 2, 2, 0><<<nbx * (HD / 64), 256, 0, stream>>>(Xn, W2t, Hb, nullptr, N, HD, HD);
  elerk<<<N / 4, 256, 0, stream>>>(Hb, al2, ar2, el, er, N);
  edgek<<<edgeBlocks, 256, 0, stream>>>(el, er, src, dst, pw, E);
  gatherk<<<gatherBlocks, 256, 0, stream>>>(Hb, pw, src, ro, b2, Xn, N, E);

  // final FC + elu -> d_out (fp32): BM=64 -> 313 blocks
  gemm_bt<64, 64, 2, 2, 1><<<nbxf, 256, 0, stream>>>(Xn, Wft, d_out, bfc, N, 64, HD);
}

// Round 11
// 205.543 us; speedup vs baseline: 1.0412x; 1.0412x over previous
//
#include <hip/hip_runtime.h>
#include <hip/hip_bf16.h>
#include <math.h>
#include <type_traits>

typedef __bf16 bf16_t;
typedef __bf16 bf16x8 __attribute__((ext_vector_type(8)));
typedef float f32x4 __attribute__((ext_vector_type(4)));

__device__ __forceinline__ void gload_lds16(const void* g, void* l) {
  __builtin_amdgcn_global_load_lds((const __attribute__((address_space(1))) void*)g,
                                   (__attribute__((address_space(3))) void*)l, 16, 0, 0);
}

// ------------- transpose + cast: in fp32 [K][N] -> out bf16 [N][K] -------------
__global__ void transk(const float* __restrict__ in, bf16_t* __restrict__ out,
                       int K, int N) {
  __shared__ float t[32][33];
  int n0 = blockIdx.x * 32, k0 = blockIdx.y * 32;
  int tx = threadIdx.x & 31, ty = threadIdx.x >> 5;  // ty 0..7
#pragma unroll
  for (int r = ty; r < 32; r += 8) t[r][tx] = in[(size_t)(k0 + r) * N + n0 + tx];
  __syncthreads();
#pragma unroll
  for (int r = ty; r < 32; r += 8)
    out[(size_t)(n0 + r) * K + k0 + tx] = (bf16_t)t[tx][r];
}

// ------------- row offsets: ro[n] = lower_bound(dst, n) (dst sorted) -------------
__global__ void rowoffk(const int* __restrict__ dst, int* __restrict__ ro, int N, int E) {
  int n = blockIdx.x * blockDim.x + threadIdx.x;
  if (n > N) return;
  if (n == N) { ro[N] = E; return; }
  int lo = 0, hi = E;
  while (lo < hi) { int mid = (lo + hi) >> 1; if (dst[mid] < n) lo = mid + 1; else hi = mid; }
  ro[n] = lo;
}

// ------------- el/er: per node, per head dot(h, al), dot(h, ar) -------------
__global__ void elerk(const bf16_t* __restrict__ Hb, const float* __restrict__ al,
                      const float* __restrict__ ar, float* __restrict__ el,
                      float* __restrict__ er, int N) {
  int node = blockIdx.x * 4 + (threadIdx.x >> 6);
  int lane = threadIdx.x & 63;
  if (node >= N) return;
  bf16x8 v = *(const bf16x8*)(Hb + (size_t)node * 512 + lane * 8);
  int head = lane >> 4;
  int dbase = (lane & 15) * 8;
  float sl = 0.f, sr = 0.f;
#pragma unroll
  for (int t = 0; t < 8; t++) {
    float f = (float)v[t];
    sl += f * al[head * 128 + dbase + t];
    sr += f * ar[head * 128 + dbase + t];
  }
#pragma unroll
  for (int off = 1; off < 16; off <<= 1) {
    sl += __shfl_xor(sl, off);
    sr += __shfl_xor(sr, off);
  }
  if ((lane & 15) == 0) {
    el[node * 4 + head] = sl;
    er[node * 4 + head] = sr;
  }
}

// ------------- edge weights (edge-parallel, streaming), per-head PLANES -------
// pw[h*E + e] = exp(leaky_relu(el[src[e]][h] + er[dst[e]][h]))
// Max-subtraction dropped (shift-invariant; scores are O(few sigma), fp32-safe).
__global__ void edgek(const float* __restrict__ el, const float* __restrict__ er,
                      const int* __restrict__ src, const int* __restrict__ dst,
                      float* __restrict__ pw, int E) {
  int e = blockIdx.x * blockDim.x + threadIdx.x;
  if (e >= E) return;
  int s = src[e], d = dst[e];
  float4 ev = *(const float4*)(el + (size_t)s * 4);
  float4 rv = *(const float4*)(er + (size_t)d * 4);
  float c;
  c = ev.x + rv.x; c = c >= 0.f ? c : 0.2f * c; pw[e] = __expf(c);
  c = ev.y + rv.y; c = c >= 0.f ? c : 0.2f * c; pw[(size_t)E + e] = __expf(c);
  c = ev.z + rv.z; c = c >= 0.f ? c : 0.2f * c; pw[(size_t)2 * E + e] = __expf(c);
  c = ev.w + rv.w; c = c >= 0.f ? c : 0.2f * c; pw[(size_t)3 * E + e] = __expf(c);
}

// ------------- gather-aggregate, DIM-SLICE x XCD partitioned, batch-8 ----------
// slice = blockIdx.x & 7 -> round-robin XCD mapping pins each 64-dim slice of
// Hb (2.56 MB) into one XCD's 4 MB L2 (verified: FETCH 140->24 MB in r6).
// lane = g*8 + oct; batch-8 contiguous src/ph loads resolve 8 gather addresses
// at once (verified: gatherk left top-5 in r8, ~20 us each).
#define GK_NPB 32  // nodes per block (4 waves x 8 groups); 20000 = 625*32
__global__ __launch_bounds__(256) void gatherk(
    const bf16_t* __restrict__ Hb, const float* __restrict__ pw,
    const int* __restrict__ src, const int* __restrict__ ro,
    const float* __restrict__ bias, bf16_t* __restrict__ out, int N, int E) {
  const int slice = blockIdx.x & 7;
  const int group = blockIdx.x >> 3;
  const int w = threadIdx.x >> 6, lane = threadIdx.x & 63;
  const int g = lane >> 3;               // node sub-index within wave
  const int oct = lane & 7;              // dim octet within slice
  const int head = slice >> 1;
  const float* __restrict__ ph = pw + (size_t)head * E;
  const int dimbase = slice * 64 + oct * 8;

  const int n = group * GK_NPB + w * 8 + g;
  const int e0 = ro[n], e1 = ro[n + 1];

  float acc[8] = {0.f, 0.f, 0.f, 0.f, 0.f, 0.f, 0.f, 0.f};
  float psum = 0.f;

  for (int eb = e0 & ~7; eb < e1; eb += 8) {
    const int4 sv0 = *(const int4*)(src + eb);
    const int4 sv1 = *(const int4*)(src + eb + 4);
    const float4 pv0 = *(const float4*)(ph + eb);
    const float4 pv1 = *(const float4*)(ph + eb + 4);
    int ss[8]; float pp[8];
    ss[0] = sv0.x; ss[1] = sv0.y; ss[2] = sv0.z; ss[3] = sv0.w;
    ss[4] = sv1.x; ss[5] = sv1.y; ss[6] = sv1.z; ss[7] = sv1.w;
    pp[0] = pv0.x; pp[1] = pv0.y; pp[2] = pv0.z; pp[3] = pv0.w;
    pp[4] = pv1.x; pp[5] = pv1.y; pp[6] = pv1.z; pp[7] = pv1.w;
#pragma unroll
    for (int j = 0; j < 8; j++) {
      const int e = eb + j;
      if (e < e0 || e >= e1) pp[j] = 0.f;
    }
    bf16x8 v[8];
#pragma unroll
    for (int j = 0; j < 8; j++)
      v[j] = *(const bf16x8*)(Hb + (size_t)ss[j] * 512 + dimbase);
#pragma unroll
    for (int j = 0; j < 8; j++) {
      psum += pp[j];
#pragma unroll
      for (int t = 0; t < 8; t++) acc[t] += pp[j] * (float)v[j][t];
    }
  }

  const float ih = psum > 0.f ? 1.0f / psum : 0.f;
  const float4 b0 = *(const float4*)(bias + dimbase);
  const float4 b1 = *(const float4*)(bias + dimbase + 4);
  bf16x8 o; float vv;
  vv = acc[0] * ih + b0.x; o[0] = (bf16_t)(vv > 0.f ? vv : expm1f(vv));
  vv = acc[1] * ih + b0.y; o[1] = (bf16_t)(vv > 0.f ? vv : expm1f(vv));
  vv = acc[2] * ih + b0.z; o[2] = (bf16_t)(vv > 0.f ? vv : expm1f(vv));
  vv = acc[3] * ih + b0.w; o[3] = (bf16_t)(vv > 0.f ? vv : expm1f(vv));
  vv = acc[4] * ih + b1.x; o[4] = (bf16_t)(vv > 0.f ? vv : expm1f(vv));
  vv = acc[5] * ih + b1.y; o[5] = (bf16_t)(vv > 0.f ? vv : expm1f(vv));
  vv = acc[6] * ih + b1.z; o[6] = (bf16_t)(vv > 0.f ? vv : expm1f(vv));
  vv = acc[7] * ih + b1.w; o[7] = (bf16_t)(vv > 0.f ? vv : expm1f(vv));
  *(bf16x8*)(out + (size_t)n * 512 + dimbase) = o;
}

// ------------- bf16 MFMA GEMM: C[M][N] = A[M][K] @ Bt[N][K]^T -------------
// BM=128/BN=128 (r10 lesson: BN=64 halves MFMA/barrier -> +40 us; reverted).
// AF32=1: A is fp32, staged via the SAME async global_load_lds path as B
// (drains at the step barrier like the proven bf16 path; r8/r9's sync
// load->cvt->ds_write chain is gone). fp32 sA row = 128 B = bank-degenerate,
// so segments are XOR-swizzled: logical seg s of row r lives at phys s^(r&7);
// gload_lds dest stays linear, the SOURCE address carries the inverse swizzle
// (lane l fetches logical seg (l&7)^(l>>3)), reads apply the same XOR ->
// 8 lanes/bank-group (optimal). cvt fp32->bf16 at fragment read (VALU idle).
// EPI=0: store bf16 C.  EPI=1: store fp32 elu(C+bias) (final FC).
template <int BM, int BN, int WM, int WN, int EPI, int AF32>
__global__ __launch_bounds__(256) void gemm_bt(
    const void* __restrict__ A, const bf16_t* __restrict__ Bt,
    void* __restrict__ C, const float* __restrict__ bias,
    int M, int N, int K) {
  constexpr int BK = 32;
  constexpr int WTM = BM / WM, WTN = BN / WN;
  constexpr int MF = WTM / 16, NF = WTN / 16;
  using AT = typename std::conditional<AF32, float, bf16_t>::type;

  __shared__ AT sA[BM][BK];
  __shared__ bf16_t sB[BN][BK];

  const bf16_t* __restrict__ Ab = (const bf16_t*)A;
  const float* __restrict__ Af = (const float*)A;

  const int tid = threadIdx.x;
  const int wid = tid >> 6, lane = tid & 63;
  const int wr = wid / WN, wc = wid % WN;

  // XCD-chunked bijective swizzle (m204)
  const int nby = N / BN;
  const int nwg = gridDim.x;
  const int q = nwg >> 3, r = nwg & 7;
  const int xcd = blockIdx.x & 7, pos = blockIdx.x >> 3;
  const int wg = (xcd < r ? xcd * (q + 1) : r * (q + 1) + (xcd - r) * q) + pos;
  const int row0 = (wg / nby) * BM;
  const int col0 = (wg % nby) * BN;

  f32x4 acc[MF][NF];
#pragma unroll
  for (int i = 0; i < MF; i++)
#pragma unroll
    for (int j = 0; j < NF; j++) acc[i][j] = (f32x4){0.f, 0.f, 0.f, 0.f};

  const int lr = lane >> 2;          // bf16 staging: row within 16-row group
  const int lkb = (lane & 3) * 8;    // bf16 staging: k element offset
  // AF32 staging: 8 rows/wave-issue; lane l -> row +l>>3, logical seg (l&7)^(l>>3)
  const int a_lr = lane >> 3;
  const int a_seg = (lane & 7) ^ (lane >> 3);

  for (int k0 = 0; k0 < K; k0 += BK) {
    if constexpr (AF32) {
#pragma unroll
      for (int j = 0; j < BM / 32; j++) {      // 4 issues per wave (BM=128)
        const int rj = (j * 4 + wid) * 8;      // row-group base (multiple of 8)
        int grow = row0 + rj + a_lr; if (grow > M - 1) grow = M - 1;
        gload_lds16(Af + (size_t)grow * K + k0 + a_seg * 4, &sA[rj][0]);
      }
    } else {
#pragma unroll
      for (int i = 0; i < BM / 16; i += 4) {
        int r2 = (i + wid) * 16 + lr;
        int grow = row0 + r2; if (grow > M - 1) grow = M - 1;
        gload_lds16(Ab + (size_t)grow * K + k0 + lkb, &sA[(i + wid) * 16][0]);
      }
    }
#pragma unroll
    for (int i = 0; i < BN / 16; i += 4) {
      int r2 = (i + wid) * 16 + lr;
      gload_lds16(Bt + (size_t)(col0 + r2) * K + k0 + lkb, &sB[(i + wid) * 16][0]);
    }
    __syncthreads();
    bf16x8 af[MF], bfr[NF];
#pragma unroll
    for (int i = 0; i < MF; i++) {
      const int row = wr * WTM + i * 16 + (lane & 15);
      if constexpr (AF32) {
        const int h = lane >> 4;
        const int rowm = row & 7;
        const int p0 = (2 * h) ^ rowm, p1 = (2 * h + 1) ^ rowm;
        const f32x4 a0 = *(const f32x4*)&((const float*)&sA[row][0])[p0 * 4];
        const f32x4 a1 = *(const f32x4*)&((const float*)&sA[row][0])[p1 * 4];
#pragma unroll
        for (int t = 0; t < 4; t++) {
          af[i][t] = (bf16_t)a0[t];
          af[i][t + 4] = (bf16_t)a1[t];
        }
      } else {
        af[i] = *(const bf16x8*)&((const bf16_t*)&sA[row][0])[(lane >> 4) * 8];
      }
    }
#pragma unroll
    for (int j = 0; j < NF; j++)
      bfr[j] = *(const bf16x8*)&sB[wc * WTN + j * 16 + (lane & 15)][(lane >> 4) * 8];
#pragma unroll
    for (int i = 0; i < MF; i++)
#pragma unroll
      for (int j = 0; j < NF; j++)
        acc[i][j] = __builtin_amdgcn_mfma_f32_16x16x32_bf16(af[i], bfr[j], acc[i][j], 0, 0, 0);
    __syncthreads();
  }

#pragma unroll
  for (int i = 0; i < MF; i++) {
#pragma unroll
    for (int j = 0; j < NF; j++) {
#pragma unroll
      for (int rr = 0; rr < 4; rr++) {
        int row = row0 + wr * WTM + i * 16 + (lane >> 4) * 4 + rr;
        int col = col0 + wc * WTN + j * 16 + (lane & 15);
        if (row < M) {
          float v = acc[i][j][rr];
          if constexpr (EPI == 0) {
            ((bf16_t*)C)[(size_t)row * N + col] = (bf16_t)v;
          } else {
            v += bias[col];
            v = v > 0.f ? v : expm1f(v);
            ((float*)C)[(size_t)row * N + col] = v;
          }
        }
      }
    }
  }
}

extern "C" void kernel_launch(void* const* d_in, const int* in_sizes, int n_in,
                              void* d_out, int out_size, void* d_ws, size_t ws_size,
                              hipStream_t stream) {
  const float* feature = (const float*)d_in[0];
  const int* src = (const int*)d_in[1];
  const int* dst = (const int*)d_in[2];
  const float* W1 = (const float*)d_in[3];
  const float* al1 = (const float*)d_in[4];
  const float* ar1 = (const float*)d_in[5];
  const float* b1 = (const float*)d_in[6];
  const float* W2 = (const float*)d_in[7];
  const float* al2 = (const float*)d_in[8];
  const float* ar2 = (const float*)d_in[9];
  const float* b2 = (const float*)d_in[10];
  const float* Wfc = (const float*)d_in[11];
  const float* bfc = (const float*)d_in[12];

  const int N = 20000, E = 320000, INF = 1280, HD = 512;

  char* ws = (char*)d_ws;
  size_t off = 0;
  auto alloc = [&](size_t bytes) {
    void* p = ws + off;
    off += (bytes + 255) & ~(size_t)255;
    return p;
  };
  bf16_t* W1t = (bf16_t*)alloc((size_t)HD * INF * 2);
  bf16_t* W2t = (bf16_t*)alloc((size_t)HD * HD * 2);
  bf16_t* Wft = (bf16_t*)alloc((size_t)64 * HD * 2);
  bf16_t* Hb  = (bf16_t*)alloc((size_t)N * HD * 2);    // 20.5 MB
  bf16_t* Xn  = (bf16_t*)alloc((size_t)N * HD * 2);    // 20.5 MB
  float* el = (float*)alloc((size_t)N * 4 * 4);
  float* er = (float*)alloc((size_t)N * 4 * 4);
  float* pw = (float*)alloc((size_t)E * 4 * 4);        // 5.1 MB, planes [4][E]
  int* ro = (int*)alloc((size_t)(N + 1) * 4);

  // preprocessing
  {
    dim3 g(HD / 32, INF / 32);
    transk<<<g, 256, 0, stream>>>(W1, W1t, INF, HD);
  }
  {
    dim3 g(HD / 32, HD / 32);
    transk<<<g, 256, 0, stream>>>(W2, W2t, HD, HD);
  }
  {
    dim3 g(64 / 32, HD / 32);
    transk<<<g, 256, 0, stream>>>(Wfc, Wft, HD, 64);
  }
  rowoffk<<<(N + 1 + 255) / 256, 256, 0, stream>>>(dst, ro, N, E);

  const int nbx = (N + 127) / 128;        // 157
  const int gatherBlocks = (N / GK_NPB) * 8;   // 625 groups x 8 slices
  const int edgeBlocks = (E + 255) / 256;

  // layer 1: A = fp32 feature staged async via global_load_lds (cast fused)
  gemm_bt<128, 128, 2, 2, 0, 1><<<nbx * (HD / 128), 256, 0, stream>>>(
      feature, W1t, Hb, nullptr, N, HD, INF);
  elerk<<<N / 4, 256, 0, stream>>>(Hb, al1, ar1, el, er, N);
  edgek<<<edgeBlocks, 256, 0, stream>>>(el, er, src, dst, pw, E);
  gatherk<<<gatherBlocks, 256, 0, stream>>>(Hb, pw, src, ro, b1, Xn, N, E);

  // layer 2: bf16 path, BN=128
  gemm_bt<128, 128, 2, 2, 0, 0><<<nbx * (HD / 128), 256, 0, stream>>>(
      Xn, W2t, Hb, nullptr, N, HD, HD);
  elerk<<<N / 4, 256, 0, stream>>>(Hb, al2, ar2, el, er, N);
  edgek<<<edgeBlocks, 256, 0, stream>>>(el, er, src, dst, pw, E);
  gatherk<<<gatherBlocks, 256, 0, stream>>>(Hb, pw, src, ro, b2, Xn, N, E);

  // final FC + elu -> d_out (fp32): r7 config
  gemm_bt<128, 64, 4, 1, 1, 0><<<nbx, 256, 0, stream>>>(Xn, Wft, d_out, bfc, N, 64, HD);
}